// Round 1
// baseline (606.490 us; speedup 1.0000x reference)
//
#include <hip/hip_runtime.h>
#include <hip/hip_bf16.h>

typedef unsigned short u16;
typedef __bf16 bf8 __attribute__((ext_vector_type(8)));
typedef float f4 __attribute__((ext_vector_type(4)));

__device__ __forceinline__ u16 f2bf(float f) {
    unsigned int u = __float_as_uint(f);
    u = (u + 0x7fffu + ((u >> 16) & 1u)) >> 16;   // RNE
    return (u16)u;
}

__device__ __forceinline__ void gload16(const u16* g, u16* l) {
    __builtin_amdgcn_global_load_lds((const __attribute__((address_space(1))) void*)g,
                                     (__attribute__((address_space(3))) void*)l, 16, 0, 0);
}

// ---------------- x fp32 -> bf16 ----------------
__global__ void cvt_x_kernel(const float* __restrict__ in, u16* __restrict__ out, int n4) {
    int i = blockIdx.x * blockDim.x + threadIdx.x;
    int stride = gridDim.x * blockDim.x;
    for (; i < n4; i += stride) {
        float4 v = ((const float4*)in)[i];
        ushort4 o;
        o.x = f2bf(v.x); o.y = f2bf(v.y); o.z = f2bf(v.z); o.w = f2bf(v.w);
        ((ushort4*)out)[i] = o;
    }
}

// ------------- [E][R][C] f32 -> [E][C][R] bf16 -------------
__global__ void transpose_cvt_kernel(const float* __restrict__ in, u16* __restrict__ out,
                                     int R, int C) {
    __shared__ float t[32][33];
    int e = blockIdx.z;
    int c0 = blockIdx.x * 32, r0 = blockIdx.y * 32;
    int tx = threadIdx.x & 31, ty = threadIdx.x >> 5;  // ty 0..7
    const float* ip = in + (size_t)e * R * C;
    u16* op = out + (size_t)e * R * C;
#pragma unroll
    for (int k = 0; k < 32; k += 8)
        t[ty + k][tx] = ip[(size_t)(r0 + ty + k) * C + c0 + tx];
    __syncthreads();
#pragma unroll
    for (int k = 0; k < 32; k += 8)
        op[(size_t)(c0 + ty + k) * R + r0 + tx] = f2bf(t[tx][ty + k]);
}

// ---------------- gating (fp32, exact semantics) ----------------
// gate[b][e] = softmax_e(G[b,e,scene[b]]) * select[b,e]
// G[b,e,s] = softmax_s( sum_d xc[b,d] * S[s,d,e] )
__global__ void gating_kernel(const float* __restrict__ x, const int* __restrict__ scene,
                              const float* __restrict__ S, const float* __restrict__ semb,
                              float* __restrict__ gate) {
    __shared__ float xc[4][1040];
    __shared__ float Lsh[4][49];
    int wv = threadIdx.x >> 6, lane = threadIdx.x & 63;
    int row = blockIdx.x * 4 + wv;
    float* xcw = xc[wv];
    const float* xr = x + (size_t)row * 1024;
    for (int d = lane; d < 1024; d += 64) xcw[d] = xr[d];
    int sc = scene[row];
    if (lane < 16) xcw[1024 + lane] = semb[sc * 16 + lane];
    __syncthreads();

    if (lane < 49) {
        int e = lane % 7, s = lane / 7;
        const float* Sp = S + s * 7280 + e;   // S[s][d][e], stride 7 over d
        float a0 = 0.f, a1 = 0.f, a2 = 0.f, a3 = 0.f;
        for (int d = 0; d < 1040; d += 4) {
            a0 += xcw[d]     * Sp[d * 7];
            a1 += xcw[d + 1] * Sp[d * 7 + 7];
            a2 += xcw[d + 2] * Sp[d * 7 + 14];
            a3 += xcw[d + 3] * Sp[d * 7 + 21];
        }
        Lsh[wv][lane] = (a0 + a1) + (a2 + a3);
    }
    __syncthreads();

    if (lane == 0) {
        float logG[7][7], Gsc[7], piS[7], qS[7];
        for (int e = 0; e < 7; e++) {
            float L[7];
            float m = -1e30f;
            for (int s = 0; s < 7; s++) { L[s] = Lsh[wv][s * 7 + e]; m = fmaxf(m, L[s]); }
            float sum = 0.f;
            for (int s = 0; s < 7; s++) sum += __expf(L[s] - m) * 0.f + expf(L[s] - m);
            float lse = m + logf(sum);
            float qs = 0.f;
            for (int s = 0; s < 7; s++) { logG[e][s] = L[s] - lse; qs += logG[e][s]; }
            piS[e] = logG[e][sc];
            qS[e] = qs;                 // monotone transform of q (same top-k)
            Gsc[e] = expf(logG[e][sc]);
        }
        // excluded index for pi: argmin with ties -> largest index (<= update)
        int epi = 0, eqi = 0; float bp = piS[0], bq = qS[0];
        for (int e = 1; e < 7; e++) {
            if (piS[e] <= bp) { bp = piS[e]; epi = e; }
            if (qS[e]  <= bq) { bq = qS[e];  eqi = e; }
        }
        float mg = -1e30f;
        for (int e = 0; e < 7; e++) mg = fmaxf(mg, Gsc[e]);
        float sum = 0.f;
        float ex[7];
        for (int e = 0; e < 7; e++) { ex[e] = expf(Gsc[e] - mg); sum += ex[e]; }
        float inv = 1.f / sum;
        for (int e = 0; e < 7; e++) {
            float g = ex[e] * inv;
            if (e == epi && e == eqi) g = 0.f;   // select mask (softmax BEFORE mask)
            gate[row * 7 + e] = g;
        }
    }
}

// ---------------- GEMM1: h[e] = relu(x @ W1[e] + b1[e]), bf16 out ----------------
// A: x_bf16 [4096][1024]  BT: W1T [7][2048][1024]  H: [7][4096][2048]
__global__ __launch_bounds__(256, 2) void gemm1_kernel(
    const u16* __restrict__ A, const u16* __restrict__ BT,
    const float* __restrict__ b1, u16* __restrict__ H) {
    const int M = 4096, K = 1024, N = 2048;
    int e = blockIdx.z;
    int bm = blockIdx.y, bn = blockIdx.x;
    __shared__ __align__(16) u16 As[128 * 32];
    __shared__ __align__(16) u16 Bs[128 * 32];
    int tid = threadIdx.x, lane = tid & 63, w = tid >> 6;
    int wm = w >> 1, wn = w & 1;

    const u16* Ag = A + (size_t)(bm * 128 + (tid >> 2)) * K + (tid & 3) * 8;
    const u16* Bg = BT + (size_t)e * N * K + (size_t)(bn * 128 + (tid >> 2)) * K + (tid & 3) * 8;

    f4 acc[4][4] = {};
    int arow = lane & 15, kch = (lane >> 4) * 8;
    const u16* Asr = As + (wm * 64 + arow) * 32 + kch;
    const u16* Bsr = Bs + (wn * 64 + arow) * 32 + kch;

    for (int kt = 0; kt < K; kt += 32) {
        gload16(Ag + kt,           As + tid * 8);
        gload16(Ag + kt + 64 * K,  As + tid * 8 + 64 * 32);
        gload16(Bg + kt,           Bs + tid * 8);
        gload16(Bg + kt + 64 * K,  Bs + tid * 8 + 64 * 32);
        __syncthreads();
        bf8 a[4], b[4];
#pragma unroll
        for (int mi = 0; mi < 4; mi++) a[mi] = *(const bf8*)(Asr + mi * 16 * 32);
#pragma unroll
        for (int ni = 0; ni < 4; ni++) b[ni] = *(const bf8*)(Bsr + ni * 16 * 32);
#pragma unroll
        for (int mi = 0; mi < 4; mi++)
#pragma unroll
            for (int ni = 0; ni < 4; ni++)
                acc[mi][ni] = __builtin_amdgcn_mfma_f32_16x16x32_bf16(a[mi], b[ni], acc[mi][ni], 0, 0, 0);
        __syncthreads();
    }

    int cn0 = bn * 128 + wn * 64 + (lane & 15);
    int rm0 = bm * 128 + wm * 64 + (lane >> 4) * 4;
    float bias[4];
#pragma unroll
    for (int ni = 0; ni < 4; ni++) bias[ni] = b1[e * N + cn0 + ni * 16];
    u16* Hp = H + (size_t)e * M * N;
#pragma unroll
    for (int mi = 0; mi < 4; mi++)
#pragma unroll
        for (int i = 0; i < 4; i++) {
            size_t rbase = (size_t)(rm0 + mi * 16 + i) * N;
#pragma unroll
            for (int ni = 0; ni < 4; ni++) {
                float v = acc[mi][ni][i] + bias[ni];
                Hp[rbase + cn0 + ni * 16] = f2bf(fmaxf(v, 0.f));
            }
        }
}

// ---------------- GEMM2: out = sum_e gate[:,e] * relu(h[e] @ W2[e] + b2[e]) ----------------
// H: [7][4096][2048]  W2T: [7][1024][2048]  out: [2][4096][1024]
__global__ __launch_bounds__(256, 2) void gemm2_kernel(
    const u16* __restrict__ H, const u16* __restrict__ W2T,
    const float* __restrict__ b2, const float* __restrict__ gate,
    float* __restrict__ out) {
    const int M = 4096, K = 2048, N = 1024;
    int bm = blockIdx.y, bn = blockIdx.x;          // tile 128 x 64
    __shared__ __align__(16) u16 As[128 * 32];
    __shared__ __align__(16) u16 Bs[64 * 32];
    int tid = threadIdx.x, lane = tid & 63, w = tid >> 6;
    int wm = w >> 1, wn = w & 1;

    f4 fin[4][2] = {};
    int arow = lane & 15, kch = (lane >> 4) * 8;
    const u16* Asr = As + (wm * 64 + arow) * 32 + kch;
    const u16* Bsr = Bs + (wn * 32 + arow) * 32 + kch;
    int rm0 = bm * 128 + wm * 64 + (lane >> 4) * 4;
    int cn0 = bn * 64 + wn * 32 + (lane & 15);

    for (int e = 0; e < 7; e++) {
        const u16* Ag = H + ((size_t)e * M + bm * 128 + (tid >> 2)) * K + (tid & 3) * 8;
        const u16* Bg = W2T + ((size_t)e * N + bn * 64 + (tid >> 2)) * K + (tid & 3) * 8;
        f4 acc[4][2] = {};
        for (int kt = 0; kt < K; kt += 32) {
            gload16(Ag + kt,          As + tid * 8);
            gload16(Ag + kt + 64 * K, As + tid * 8 + 64 * 32);
            gload16(Bg + kt,          Bs + tid * 8);
            __syncthreads();
            bf8 a[4], b[2];
#pragma unroll
            for (int mi = 0; mi < 4; mi++) a[mi] = *(const bf8*)(Asr + mi * 16 * 32);
#pragma unroll
            for (int ni = 0; ni < 2; ni++) b[ni] = *(const bf8*)(Bsr + ni * 16 * 32);
#pragma unroll
            for (int mi = 0; mi < 4; mi++)
#pragma unroll
                for (int ni = 0; ni < 2; ni++)
                    acc[mi][ni] = __builtin_amdgcn_mfma_f32_16x16x32_bf16(a[mi], b[ni], acc[mi][ni], 0, 0, 0);
            __syncthreads();
        }
        float bias0 = b2[e * N + cn0];
        float bias1 = b2[e * N + cn0 + 16];
#pragma unroll
        for (int mi = 0; mi < 4; mi++)
#pragma unroll
            for (int i = 0; i < 4; i++) {
                float g = gate[(rm0 + mi * 16 + i) * 7 + e];
                fin[mi][0][i] += g * fmaxf(acc[mi][0][i] + bias0, 0.f);
                fin[mi][1][i] += g * fmaxf(acc[mi][1][i] + bias1, 0.f);
            }
    }

#pragma unroll
    for (int mi = 0; mi < 4; mi++)
#pragma unroll
        for (int i = 0; i < 4; i++) {
            size_t r = (size_t)(rm0 + mi * 16 + i);
#pragma unroll
            for (int ni = 0; ni < 2; ni++) {
                float v = fin[mi][ni][i];
                size_t c = cn0 + ni * 16;
                out[r * N + c] = v;
                out[(size_t)M * N + r * N + c] = v;
            }
        }
}

extern "C" void kernel_launch(void* const* d_in, const int* in_sizes, int n_in,
                              void* d_out, int out_size, void* d_ws, size_t ws_size,
                              hipStream_t stream) {
    const float* x     = (const float*)d_in[0];
    const int*   scene = (const int*)d_in[1];
    const float* W1    = (const float*)d_in[2];
    const float* b1    = (const float*)d_in[3];
    const float* W2    = (const float*)d_in[4];
    const float* b2    = (const float*)d_in[5];
    const float* S     = (const float*)d_in[6];
    const float* semb  = (const float*)d_in[7];
    float* out = (float*)d_out;

    char* ws = (char*)d_ws;
    u16*   xb   = (u16*)(ws);                                  // 8,388,608 B
    u16*   W1T  = (u16*)(ws + 8388608);                        // 29,360,128 B
    u16*   W2T  = (u16*)(ws + 8388608 + 29360128);             // 29,360,128 B
    u16*   Hb   = (u16*)(ws + 8388608 + 2 * 29360128);         // 117,440,512 B
    float* gate = (float*)(ws + 8388608 + 2 * 29360128 + 117440512);  // 114,688 B

    cvt_x_kernel<<<2048, 256, 0, stream>>>(x, xb, 4096 * 1024 / 4);
    transpose_cvt_kernel<<<dim3(64, 32, 7), 256, 0, stream>>>(W1, W1T, 1024, 2048);
    transpose_cvt_kernel<<<dim3(32, 64, 7), 256, 0, stream>>>(W2, W2T, 2048, 1024);
    gating_kernel<<<1024, 256, 0, stream>>>(x, scene, S, semb, gate);
    gemm1_kernel<<<dim3(16, 32, 7), 256, 0, stream>>>(xb, W1T, b1, Hb);
    gemm2_kernel<<<dim3(16, 32), 256, 0, stream>>>(Hb, W2T, b2, gate, out);
}